// Round 6
// baseline (421.295 us; speedup 1.0000x reference)
//
#include <hip/hip_runtime.h>

#define N_NODES  50000
#define N_EDGES  800000
#define N_GRAPHS 128
#define DIM      128
#define K2       256
#define CLS      10
#define NB_SCAN  ((N_NODES + 255) / 256)   // 196
#define NPART    8                          // dst partitions == XCD count
#define PSIZE    (N_NODES / NPART)          // 6250
#define NCHUNK   64
#define CHUNK    (N_EDGES / NCHUNK)         // 12500

typedef __attribute__((ext_vector_type(8))) short bf16x8;
typedef __attribute__((ext_vector_type(4))) float f32x4;

__device__ inline unsigned short f2bf(float f) {
    unsigned u = __float_as_uint(f);
    unsigned r = (u + 0x7FFFu + ((u >> 16) & 1u)) >> 16;   // RNE
    return (unsigned short)r;
}
__device__ inline float bf2f(unsigned short s) {
    return __uint_as_float(((unsigned)s) << 16);
}

// ---------------- partitioned degree count (XCD-local atomics) ----------------
__global__ __launch_bounds__(256) void k_deg_p(const int* __restrict__ dst, int* __restrict__ deg) {
    const int part = blockIdx.x & (NPART - 1);
    const int lo = (blockIdx.x >> 3) * CHUNK;
    const int plo = part * PSIZE, phi = plo + PSIZE;
    for (int i = lo + threadIdx.x; i < lo + CHUNK; i += 256) {
        int d = dst[i];
        if (d >= plo && d < phi) atomicAdd(&deg[d], 1);
    }
}

// ---------------- graph counts via binary search (graph_ids sorted) ----------------
__global__ __launch_bounds__(128) void k_count_sorted(const int* __restrict__ gid, float* __restrict__ counts) {
    int g = threadIdx.x;
    int lo = 0, hi = N_NODES;
    while (lo < hi) { int mid = (lo + hi) >> 1; if (gid[mid] < g) lo = mid + 1; else hi = mid; }
    int start = lo;
    lo = 0; hi = N_NODES;
    while (lo < hi) { int mid = (lo + hi) >> 1; if (gid[mid] <= g) lo = mid + 1; else hi = mid; }
    counts[g] = (float)(lo - start);
}

// ---------------- parallel 3-phase scan ----------------
__global__ __launch_bounds__(256) void k_scan_part(const int* __restrict__ deg,
                                                   int* __restrict__ rowptr, int* __restrict__ bsum) {
    __shared__ int s[256];
    const int tid = threadIdx.x;
    const int i = blockIdx.x * 256 + tid;
    int v = (i < N_NODES) ? deg[i] : 0;
    s[tid] = v;
    __syncthreads();
    for (int off = 1; off < 256; off <<= 1) {
        int add = (tid >= off) ? s[tid - off] : 0;
        __syncthreads();
        s[tid] += add;
        __syncthreads();
    }
    if (i < N_NODES) rowptr[i] = s[tid] - v;
    if (tid == 255) bsum[blockIdx.x] = s[255];
}

__global__ __launch_bounds__(256) void k_scan_top(const int* __restrict__ bsum, int* __restrict__ boff,
                                                  int* __restrict__ rowptr) {
    __shared__ int s[256];
    const int tid = threadIdx.x;
    int v = (tid < NB_SCAN) ? bsum[tid] : 0;
    s[tid] = v;
    __syncthreads();
    for (int off = 1; off < 256; off <<= 1) {
        int add = (tid >= off) ? s[tid - off] : 0;
        __syncthreads();
        s[tid] += add;
        __syncthreads();
    }
    if (tid < NB_SCAN) boff[tid] = s[tid] - v;
    if (tid == 0) rowptr[N_NODES] = N_EDGES;
}

__global__ __launch_bounds__(256) void k_scan_add(int* __restrict__ rowptr, const int* __restrict__ boff,
                                                  int* __restrict__ cursor) {
    const int i = blockIdx.x * 256 + threadIdx.x;
    if (i < N_NODES) {
        int r = rowptr[i] + boff[blockIdx.x];
        rowptr[i] = r;
        cursor[i] = r;
    }
}

// ---------------- partitioned CSR fill (XCD-local cursor atomics + eidx stores) ----------------
__global__ __launch_bounds__(256) void k_fill_p(const int* __restrict__ src, const int* __restrict__ dst,
                                                int* __restrict__ cursor, int* __restrict__ eidx) {
    const int part = blockIdx.x & (NPART - 1);
    const int lo = (blockIdx.x >> 3) * CHUNK;
    const int plo = part * PSIZE, phi = plo + PSIZE;
    for (int i = lo + threadIdx.x; i < lo + CHUNK; i += 256) {
        int d = dst[i];
        if (d >= plo && d < phi) {
            int pos = atomicAdd(&cursor[d], 1);
            eidx[pos] = src[i];
        }
    }
}

// ---------------- features fp32 -> bf16 hcat0 h-part ----------------
__global__ __launch_bounds__(256) void k_cast(const float* __restrict__ f, unsigned short* __restrict__ c0) {
    int t = blockIdx.x * 256 + threadIdx.x;   // one per 8 elems
    if (t >= N_NODES * 16) return;
    int row = t >> 4, c8 = (t & 15) * 8;
    const float* p = f + (size_t)row * DIM + c8;
    float4 a = *(const float4*)p;
    float4 b = *(const float4*)(p + 4);
    uint4 v;
    v.x = f2bf(a.x) | ((unsigned)f2bf(a.y) << 16);
    v.y = f2bf(a.z) | ((unsigned)f2bf(a.w) << 16);
    v.z = f2bf(b.x) | ((unsigned)f2bf(b.y) << 16);
    v.w = f2bf(b.z) | ((unsigned)f2bf(b.w) << 16);
    *(uint4*)(c0 + (size_t)row * K2 + c8) = v;
}

// ---------------- weights: transpose + concat + hi/lo split ----------------
__global__ __launch_bounds__(256) void k_prep_w(const float* __restrict__ Ws0, const float* __restrict__ Wn0,
                                                const float* __restrict__ Ws1, const float* __restrict__ Wn1,
                                                const float* __restrict__ Ws2, const float* __restrict__ Wn2,
                                                unsigned short* __restrict__ hi, unsigned short* __restrict__ lo) {
    int t = blockIdx.x * 256 + threadIdx.x;
    if (t >= 3 * DIM * K2) return;
    int l = t / (DIM * K2), r = t % (DIM * K2);
    int n = r / K2, k = r % K2;
    const float* Ws = (l == 0) ? Ws0 : (l == 1) ? Ws1 : Ws2;
    const float* Wn = (l == 0) ? Wn0 : (l == 1) ? Wn1 : Wn2;
    float w = (k < DIM) ? Ws[k * DIM + n] : Wn[(k - DIM) * DIM + n];
    unsigned short h = f2bf(w);
    hi[t] = h;
    lo[t] = f2bf(w - bf2f(h));
}

// ---------------- gather: one wave per node, bf16 rows, fp32 accum ----------------
__global__ __launch_bounds__(256) void k_gather(const unsigned short* __restrict__ h,
                                                const int* __restrict__ rowptr,
                                                const int* __restrict__ eidx,
                                                unsigned short* __restrict__ msg) {
    const int node = (blockIdx.x * 256 + threadIdx.x) >> 6;
    const int lane = threadIdx.x & 63;
    if (node >= N_NODES) return;
    const int epar = lane >> 4;        // 4 edges in flight
    const int d0 = (lane & 15) * 8;    // 8 bf16 per lane = 16 B
    const int beg = rowptr[node], end = rowptr[node + 1];
    float acc[8] = {0.f, 0.f, 0.f, 0.f, 0.f, 0.f, 0.f, 0.f};
    for (int j = beg + epar; j < end; j += 4) {
        int s = eidx[j];
        uint4 v = *(const uint4*)(h + (size_t)s * K2 + d0);
        unsigned u[4] = {v.x, v.y, v.z, v.w};
#pragma unroll
        for (int i = 0; i < 4; ++i) {
            acc[2 * i]     += __uint_as_float(u[i] << 16);
            acc[2 * i + 1] += __uint_as_float(u[i] & 0xFFFF0000u);
        }
    }
#pragma unroll
    for (int i = 0; i < 8; ++i) {
        acc[i] += __shfl_xor(acc[i], 16);
        acc[i] += __shfl_xor(acc[i], 32);
    }
    if (epar == 0) {
        float inv = (end > beg) ? 1.0f / (float)(end - beg) : 0.f;
        unsigned short o[8];
#pragma unroll
        for (int i = 0; i < 8; ++i) o[i] = f2bf(acc[i] * inv);
        uint4 v;
        v.x = o[0] | ((unsigned)o[1] << 16);
        v.y = o[2] | ((unsigned)o[3] << 16);
        v.z = o[4] | ((unsigned)o[5] << 16);
        v.w = o[6] | ((unsigned)o[7] << 16);
        *(uint4*)(msg + (size_t)node * K2 + DIM + d0) = v;
    }
}

// ---------------- SAGE layer: bf16 MFMA, single K=256 GEMM ----------------
__global__ __launch_bounds__(256) void k_sage(const unsigned short* __restrict__ hin,  // [m][256]
                                              const unsigned short* __restrict__ whi,  // [n][256]
                                              const unsigned short* __restrict__ wlo,
                                              const float* __restrict__ bias,
                                              unsigned short* __restrict__ hout) {
    __shared__ unsigned short Ah[128 * 40];   // stride 40 shorts (80 B): 2-way bank alias = free
    __shared__ unsigned short Bh[128 * 40];
    __shared__ unsigned short Bl[128 * 40];
    const int tid = threadIdx.x;
    const int wv = tid >> 6, lane = tid & 63;
    const int m0 = blockIdx.x * 128;
    const int m_off = (wv >> 1) * 64, n_off = (wv & 1) * 64;
    const int l15 = lane & 15, q = lane >> 4;

    f32x4 acc[4][4];
#pragma unroll
    for (int a = 0; a < 4; ++a)
#pragma unroll
        for (int b = 0; b < 4; ++b) acc[a][b] = (f32x4){0.f, 0.f, 0.f, 0.f};

#pragma unroll 1
    for (int kt = 0; kt < 8; ++kt) {
        const int k0 = kt * 32;
#pragma unroll
        for (int i = 0; i < 2; ++i) {
            int idx = tid + i * 256;
            int row = idx >> 2, kq = (idx & 3) * 8;
            int gm = m0 + row;
            uint4 va = make_uint4(0u, 0u, 0u, 0u);
            if (gm < N_NODES) va = *(const uint4*)(hin + (size_t)gm * K2 + k0 + kq);
            *(uint4*)&Ah[row * 40 + kq] = va;
            *(uint4*)&Bh[row * 40 + kq] = *(const uint4*)(whi + (size_t)row * K2 + k0 + kq);
            *(uint4*)&Bl[row * 40 + kq] = *(const uint4*)(wlo + (size_t)row * K2 + k0 + kq);
        }
        __syncthreads();
        bf16x8 hf[4], wh[4], wl[4];
#pragma unroll
        for (int mt = 0; mt < 4; ++mt)
            hf[mt] = *(const bf16x8*)&Ah[(m_off + mt * 16 + l15) * 40 + q * 8];
#pragma unroll
        for (int nt = 0; nt < 4; ++nt) {
            wh[nt] = *(const bf16x8*)&Bh[(n_off + nt * 16 + l15) * 40 + q * 8];
            wl[nt] = *(const bf16x8*)&Bl[(n_off + nt * 16 + l15) * 40 + q * 8];
        }
#pragma unroll
        for (int mt = 0; mt < 4; ++mt)
#pragma unroll
            for (int nt = 0; nt < 4; ++nt) {
                acc[mt][nt] = __builtin_amdgcn_mfma_f32_16x16x32_bf16(wh[nt], hf[mt], acc[mt][nt], 0, 0, 0);
                acc[mt][nt] = __builtin_amdgcn_mfma_f32_16x16x32_bf16(wl[nt], hf[mt], acc[mt][nt], 0, 0, 0);
            }
        __syncthreads();
    }
#pragma unroll
    for (int nt = 0; nt < 4; ++nt) {
        int n = n_off + nt * 16 + q * 4;
        float4 bv = *(const float4*)(bias + n);
#pragma unroll
        for (int mt = 0; mt < 4; ++mt) {
            int m = m0 + m_off + mt * 16 + l15;
            if (m < N_NODES) {
                f32x4 a = acc[mt][nt];
                unsigned short o0 = f2bf(fmaxf(a[0] + bv.x, 0.f));
                unsigned short o1 = f2bf(fmaxf(a[1] + bv.y, 0.f));
                unsigned short o2 = f2bf(fmaxf(a[2] + bv.z, 0.f));
                unsigned short o3 = f2bf(fmaxf(a[3] + bv.w, 0.f));
                uint2 v;
                v.x = o0 | ((unsigned)o1 << 16);
                v.y = o2 | ((unsigned)o3 << 16);
                *(uint2*)(hout + (size_t)m * K2 + n) = v;
            }
        }
    }
}

// ---------------- graph mean-pool (bf16 h, sorted gids) ----------------
__global__ __launch_bounds__(256) void k_pool(const unsigned short* __restrict__ h,
                                              const int* __restrict__ gid,
                                              float* __restrict__ pooled) {
    int d = threadIdx.x & 127;
    int half = threadIdx.x >> 7;
    int n0 = blockIdx.x * 128;
    float acc = 0.f;
    int cur = -1;
    for (int i = half; i < 128; i += 2) {
        int n = n0 + i;
        if (n >= N_NODES) break;
        int g = gid[n];
        if (g != cur) {
            if (cur >= 0) atomicAdd(&pooled[(size_t)cur * DIM + d], acc);
            acc = 0.f;
            cur = g;
        }
        acc += bf2f(h[(size_t)n * K2 + d]);
    }
    if (cur >= 0) atomicAdd(&pooled[(size_t)cur * DIM + d], acc);
}

// ---------------- classifier (fp32) ----------------
__global__ __launch_bounds__(256) void k_final(const float* __restrict__ pooled,
                                               const float* __restrict__ counts,
                                               const float* __restrict__ Wf,
                                               const float* __restrict__ bf,
                                               float* __restrict__ out) {
    int t = blockIdx.x * 256 + threadIdx.x;
    if (t >= N_GRAPHS * CLS) return;
    int g = t / CLS, c = t % CLS;
    float inv = 1.0f / fmaxf(counts[g], 1.0f);
    float s = 0.f;
    for (int k = 0; k < DIM; ++k) s += pooled[(size_t)g * DIM + k] * Wf[k * CLS + c];
    out[t] = s * inv + bf[c];
}

extern "C" void kernel_launch(void* const* d_in, const int* in_sizes, int n_in,
                              void* d_out, int out_size, void* d_ws, size_t ws_size,
                              hipStream_t stream) {
    const float* features = (const float*)d_in[0];
    const int*   esrc     = (const int*)d_in[1];
    const int*   edst     = (const int*)d_in[2];
    const int*   gids     = (const int*)d_in[3];
    const float* bs[3]  = {(const float*)d_in[6], (const float*)d_in[9], (const float*)d_in[12]};
    const float* Wf = (const float*)d_in[13];
    const float* bfv = (const float*)d_in[14];
    float* out = (float*)d_out;

    // ---- workspace layout ----
    int* deg_i  = (int*)d_ws;            // 50048
    int* rowptr = deg_i + 50048;         // 50064
    int* cursor = rowptr + 50064;        // 50048
    int* bsum   = cursor + 50048;        // 256
    int* boff   = bsum + 256;            // 256
    int* eidx   = boff + 256;            // 800000
    float* pooled = (float*)(eidx + 800000);     // 16384
    float* counts = pooled + N_GRAPHS * DIM;     // 128
    unsigned short* C0  = (unsigned short*)(counts + 128);        // 50000*256 bf16
    unsigned short* C1  = C0 + (size_t)N_NODES * K2;
    unsigned short* C2  = C1 + (size_t)N_NODES * K2;
    unsigned short* Whi = C2 + (size_t)N_NODES * K2;              // 3*128*256
    unsigned short* Wlo = Whi + 3 * DIM * K2;

    hipMemsetAsync(deg_i, 0, 50048 * sizeof(int), stream);
    hipMemsetAsync(pooled, 0, N_GRAPHS * DIM * sizeof(float), stream);

    // CSR build (XCD-partitioned) + precompute
    k_deg_p<<<NPART * NCHUNK, 256, 0, stream>>>(edst, deg_i);
    k_count_sorted<<<1, 128, 0, stream>>>(gids, counts);
    k_scan_part<<<NB_SCAN, 256, 0, stream>>>(deg_i, rowptr, bsum);
    k_scan_top<<<1, 256, 0, stream>>>(bsum, boff, rowptr);
    k_scan_add<<<NB_SCAN, 256, 0, stream>>>(rowptr, boff, cursor);
    k_fill_p<<<NPART * NCHUNK, 256, 0, stream>>>(esrc, edst, cursor, eidx);
    k_cast<<<(N_NODES * 16 + 255) / 256, 256, 0, stream>>>(features, C0);
    k_prep_w<<<(3 * DIM * K2 + 255) / 256, 256, 0, stream>>>(
        (const float*)d_in[4], (const float*)d_in[5],
        (const float*)d_in[7], (const float*)d_in[8],
        (const float*)d_in[10], (const float*)d_in[11], Whi, Wlo);

    unsigned short* C[4] = {C0, C1, C2, C0};
    for (int l = 0; l < 3; ++l) {
        k_gather<<<(N_NODES * 64 + 255) / 256, 256, 0, stream>>>(C[l], rowptr, eidx, C[l]);
        k_sage<<<(N_NODES + 127) / 128, 256, 0, stream>>>(
            C[l], Whi + (size_t)l * DIM * K2, Wlo + (size_t)l * DIM * K2, bs[l], C[l + 1]);
    }

    k_pool<<<(N_NODES + 127) / 128, 256, 0, stream>>>(C0, gids, pooled);
    k_final<<<(N_GRAPHS * CLS + 255) / 256, 256, 0, stream>>>(pooled, counts, Wf, bfv, out);
}